// Round 3
// baseline (502.543 us; speedup 1.0000x reference)
//
#include <hip/hip_runtime.h>
#include <math.h>

// ---------------------------------------------------------------------------
// DiffTransformer encoder layer, MI355X bf16 MFMA. Round 3:
//  - attention: barrier-free, LDS-free. K/V/Q fragments loaded directly
//    global->VGPR (L2-resident, head-per-XCD grid swizzle). P transposed
//    C-layout -> A-layout with ds_bpermute (pure quad permutation).
//    2-wave blocks (64 q), grid 48x16 = 768 = 3*256 (balanced, co-resident).
//  - proj/fc2 (F=768) use 64x128 tiles -> grid 384 (was 192, grid-starved).
// B=4 N=1024 C=768 H=12 D=64 (2D=128). LAMBDA_INIT=0.2.
// ---------------------------------------------------------------------------

typedef __bf16 bf16_t;
typedef __attribute__((ext_vector_type(8))) __bf16 bf16x8;
typedef __attribute__((ext_vector_type(4))) __bf16 bf16x4;
typedef __attribute__((ext_vector_type(2))) __bf16 bf16x2;
typedef __attribute__((ext_vector_type(4))) float  floatx4;

constexpr int Bb = 4, Nn = 1024, Cc = 768, Hh = 12;
constexpr int Rr = Bb * Nn;  // 4096 rows
constexpr float EPS_ = 1e-5f;
// exp(s*0.125) == exp2(s*0.125*log2(e)); folded into wq at convert time.
constexpr float QSCALE_ = 0.125f * 1.4426950408889634f;

__device__ __forceinline__ floatx4 mfma16(bf16x8 a, bf16x8 b, floatx4 c) {
  return __builtin_amdgcn_mfma_f32_16x16x32_bf16(a, b, c, 0, 0, 0);
}

// async global->LDS, 16 B per lane; lane i's data lands at lds + i*16B.
__device__ __forceinline__ void async16(bf16_t* lds, const bf16_t* g) {
  __builtin_amdgcn_global_load_lds(
      (__attribute__((address_space(1))) void*)g,
      (__attribute__((address_space(3))) void*)lds, 16, 0, 0);
}

__device__ __forceinline__ int pack2bf(float a, float b) {
  bf16x2 v; v[0] = (__bf16)a; v[1] = (__bf16)b;
  int r; __builtin_memcpy(&r, &v, 4); return r;
}

__device__ __forceinline__ bf16x8 as_frag(const int* p) {
  union { int i[4]; bf16x8 v; } u;
  u.i[0] = p[0]; u.i[1] = p[1]; u.i[2] = p[2]; u.i[3] = p[3];
  return u.v;
}

// ---------------------------------------------------------------------------
// Weights f32 -> bf16, contiguous: wq|wk|wv|proj|fc1|fc2. wq scaled by QSCALE_.
// ---------------------------------------------------------------------------
__global__ __launch_bounds__(256) void convert_weights(
    const float* __restrict__ s0, const float* __restrict__ s1,
    const float* __restrict__ s2, const float* __restrict__ s3,
    const float* __restrict__ s4, const float* __restrict__ s5,
    bf16_t* __restrict__ dst) {
  const size_t e = ((size_t)blockIdx.x * 256 + threadIdx.x) * 4;
  const float* src; size_t off; float sc = 1.0f;
  if      (e < 1179648u) { src = s0; off = e;            sc = QSCALE_; }
  else if (e < 2359296u) { src = s1; off = e - 1179648u; }
  else if (e < 3538944u) { src = s2; off = e - 2359296u; }
  else if (e < 4718592u) { src = s3; off = e - 3538944u; }
  else if (e < 7077888u) { src = s4; off = e - 4718592u; }
  else                   { src = s5; off = e - 7077888u; }
  const float4 f = *(const float4*)(src + off);
  bf16x4 o;
  o[0] = (__bf16)(f.x * sc); o[1] = (__bf16)(f.y * sc);
  o[2] = (__bf16)(f.z * sc); o[3] = (__bf16)(f.w * sc);
  *(bf16x4*)(dst + e) = o;
}

// ---------------------------------------------------------------------------
// Row LayerNorm (row length 768) f32 -> bf16. One block per row.
// ---------------------------------------------------------------------------
__global__ __launch_bounds__(256) void ln_kernel(
    const float* __restrict__ x, const float* __restrict__ w,
    const float* __restrict__ b, bf16_t* __restrict__ out) {
  const int row = blockIdx.x, t = threadIdx.x;
  const float* xr = x + (size_t)row * Cc;
  const float v0 = xr[t], v1 = xr[t + 256], v2 = xr[t + 512];
  float s  = v0 + v1 + v2;
  float s2 = v0 * v0 + v1 * v1 + v2 * v2;
#pragma unroll
  for (int off = 32; off > 0; off >>= 1) {
    s  += __shfl_down(s, off);
    s2 += __shfl_down(s2, off);
  }
  __shared__ float ws_[4], ws2_[4];
  if ((t & 63) == 0) { ws_[t >> 6] = s; ws2_[t >> 6] = s2; }
  __syncthreads();
  const float S  = ws_[0] + ws_[1] + ws_[2] + ws_[3];
  const float S2 = ws2_[0] + ws2_[1] + ws2_[2] + ws2_[3];
  const float mu  = S * (1.0f / Cc);
  const float inv = rsqrtf(S2 * (1.0f / Cc) - mu * mu + EPS_);
  bf16_t* orow = out + (size_t)row * Cc;
  orow[t]       = (bf16_t)((v0 - mu) * inv * w[t]       + b[t]);
  orow[t + 256] = (bf16_t)((v1 - mu) * inv * w[t + 256] + b[t + 256]);
  orow[t + 512] = (bf16_t)((v2 - mu) * inv * w[t + 512] + b[t + 512]);
}

// ---------------------------------------------------------------------------
// bf16 MFMA GEMM, m97 structure: 128x128 tile, BK=32, unpadded LDS,
// global_load_lds staging. EPI: 0 = fused qkv scatter, 3 = gelu->bf16.
// ---------------------------------------------------------------------------
template <int EPI>
__global__ __launch_bounds__(256, 3) void gemm_kernel(
    const bf16_t* __restrict__ A, const bf16_t* __restrict__ W,
    int K, int F,
    const float* __restrict__ bias, void* __restrict__ outp) {
  __shared__ alignas(16) bf16_t ldsA[128 * 32];
  __shared__ alignas(16) bf16_t ldsB[128 * 32];
  const int t = threadIdx.x, wave = t >> 6, lane = t & 63;
  const int quad = lane >> 4, l16 = lane & 15;
  const int wm = (wave & 1) * 64, wn = (wave >> 1) * 64;
  const int f0 = blockIdx.x * 128, r0 = blockIdx.y * 128;
  const int srow = lane >> 2, scol = (lane & 3) * 8;

  const bf16_t* ga0 = A + (size_t)(r0 + wave * 32 + srow) * K + scol;
  const bf16_t* ga1 = ga0 + (size_t)16 * K;
  const bf16_t* gb0 = W + (size_t)(f0 + wave * 32 + srow) * K + scol;
  const bf16_t* gb1 = gb0 + (size_t)16 * K;
  bf16_t* la0 = &ldsA[(wave * 2 + 0) * 512];
  bf16_t* la1 = &ldsA[(wave * 2 + 1) * 512];
  bf16_t* lb0 = &ldsB[(wave * 2 + 0) * 512];
  bf16_t* lb1 = &ldsB[(wave * 2 + 1) * 512];

  floatx4 acc[4][4] = {};

  for (int k0 = 0; k0 < K; k0 += 32) {
    __syncthreads();
    async16(la0, ga0 + k0);
    async16(la1, ga1 + k0);
    async16(lb0, gb0 + k0);
    async16(lb1, gb1 + k0);
    __syncthreads();

    bf16x8 af[4], bfr[4];
#pragma unroll
    for (int mt = 0; mt < 4; mt++)
      af[mt] = *(const bf16x8*)&ldsA[(wm + mt * 16 + l16) * 32 + quad * 8];
#pragma unroll
    for (int nt = 0; nt < 4; nt++)
      bfr[nt] = *(const bf16x8*)&ldsB[(wn + nt * 16 + l16) * 32 + quad * 8];
#pragma unroll
    for (int mt = 0; mt < 4; mt++)
#pragma unroll
      for (int nt = 0; nt < 4; nt++)
        acc[mt][nt] = mfma16(af[mt], bfr[nt], acc[mt][nt]);
  }

#pragma unroll
  for (int mt = 0; mt < 4; mt++) {
#pragma unroll
    for (int nt = 0; nt < 4; nt++) {
#pragma unroll
      for (int rg = 0; rg < 4; rg++) {
        const int r = r0 + wm + mt * 16 + quad * 4 + rg;
        const int f = f0 + wn + nt * 16 + l16;
        const float v = acc[mt][nt][rg];
        if constexpr (EPI == 0) {
          const int b = r >> 10, n = r & 1023;
          bf16_t* qkv = (bf16_t*)outp;
          if (f < 1536) {
            const int h = f >> 7, d = f & 127;
            qkv[(((size_t)(b * Hh + h)) * Nn + n) * 128 + d] = (bf16_t)v;
          } else if (f < 3072) {
            const int f2 = f - 1536, h = f2 >> 7, d = f2 & 127;
            (qkv + (size_t)Rr * 1536)
                [(((size_t)(b * Hh + h)) * Nn + n) * 128 + d] = (bf16_t)v;
          } else {
            const int f2 = f - 3072, h = f2 >> 7, d = f2 & 127;
            (qkv + (size_t)2 * Rr * 1536)
                [(((size_t)(b * Hh + h)) * 128 + d) * Nn + n] = (bf16_t)v;
          }
        } else {
          const float z = v + bias[f];
          const float g = 0.5f * z * (1.0f + erff(z * 0.70710678118f));
          ((bf16_t*)outp)[(size_t)r * F + f] = (bf16_t)g;
        }
      }
    }
  }
}

// ---------------------------------------------------------------------------
// 64x128-tile GEMM for F=768 outputs (proj, fc2): grid (6, 64) = 384 blocks.
// f32 out = acc + bias[f] + resid[r*F+f].
// ---------------------------------------------------------------------------
__global__ __launch_bounds__(256, 4) void gemm64_kernel(
    const bf16_t* __restrict__ A, const bf16_t* __restrict__ W,
    int K, int F,
    const float* __restrict__ bias, const float* __restrict__ resid,
    float* __restrict__ outp) {
  __shared__ alignas(16) bf16_t ldsA[64 * 32];
  __shared__ alignas(16) bf16_t ldsB[128 * 32];
  const int t = threadIdx.x, wave = t >> 6, lane = t & 63;
  const int quad = lane >> 4, l16 = lane & 15;
  const int wm = (wave & 1) * 32, wn = (wave >> 1) * 64;
  const int f0 = blockIdx.x * 128, r0 = blockIdx.y * 64;
  const int srow = lane >> 2, scol = (lane & 3) * 8;

  const bf16_t* ga = A + (size_t)(r0 + wave * 16 + srow) * K + scol;
  const bf16_t* gb0 = W + (size_t)(f0 + wave * 32 + srow) * K + scol;
  const bf16_t* gb1 = gb0 + (size_t)16 * K;
  bf16_t* la  = &ldsA[wave * 512];
  bf16_t* lb0 = &ldsB[(wave * 2 + 0) * 512];
  bf16_t* lb1 = &ldsB[(wave * 2 + 1) * 512];

  floatx4 acc[2][4] = {};

  for (int k0 = 0; k0 < K; k0 += 32) {
    __syncthreads();
    async16(la, ga + k0);
    async16(lb0, gb0 + k0);
    async16(lb1, gb1 + k0);
    __syncthreads();

    bf16x8 af[2], bfr[4];
#pragma unroll
    for (int mt = 0; mt < 2; mt++)
      af[mt] = *(const bf16x8*)&ldsA[(wm + mt * 16 + l16) * 32 + quad * 8];
#pragma unroll
    for (int nt = 0; nt < 4; nt++)
      bfr[nt] = *(const bf16x8*)&ldsB[(wn + nt * 16 + l16) * 32 + quad * 8];
#pragma unroll
    for (int mt = 0; mt < 2; mt++)
#pragma unroll
      for (int nt = 0; nt < 4; nt++)
        acc[mt][nt] = mfma16(af[mt], bfr[nt], acc[mt][nt]);
  }

#pragma unroll
  for (int mt = 0; mt < 2; mt++)
#pragma unroll
    for (int nt = 0; nt < 4; nt++)
#pragma unroll
      for (int rg = 0; rg < 4; rg++) {
        const int r = r0 + wm + mt * 16 + quad * 4 + rg;
        const int f = f0 + wn + nt * 16 + l16;
        outp[(size_t)r * F + f] =
            acc[mt][nt][rg] + bias[f] + resid[(size_t)r * F + f];
      }
}

// ---------------------------------------------------------------------------
// Differential attention v3: barrier-free, LDS-free.
// Block = 2 waves x 32 q = 64 q, one head. grid (48 bh, 16 qblk) so all
// q-blocks of a head share an XCD (bh%8) -> K/V L2-resident (6 heads x 512KB
// streamed in 32KB/kt windows per XCD L2).
// S^T: A=K-frag (global), B=Q-frag (regs) -> C holds (key=quad*4+rg, q=l16).
// P = exp2(S) packed to bf16 pairs; C->A-layout transpose is a quad
// permutation: A-reg i of lane(quad,l16) = pk[t=2c32+(quad>>1)][h=i&1] pulled
// from lane ((quad&1)*2+(i>>1))*16+l16 -> 2x ds_bpermute + cndmask.
// PV: A=P (regs), B=V^T-frag (global). No __syncthreads anywhere.
// No running max: |s*log2e/8| < ~8, exp2 safe in f32; softmax shift-invariant.
// ---------------------------------------------------------------------------
__global__ __launch_bounds__(128, 2) void attn_kernel(
    const bf16_t* __restrict__ Q, const bf16_t* __restrict__ Kk,
    const bf16_t* __restrict__ Vt, const float* __restrict__ lam,
    const float* __restrict__ lnw, const float* __restrict__ lnb,
    bf16_t* __restrict__ outp) {
  const int bh = blockIdx.x, qblk = blockIdx.y;
  const bf16_t* qp = Q  + (size_t)bh * Nn * 128;   // [n][d]
  const bf16_t* kp = Kk + (size_t)bh * Nn * 128;   // [n][d]
  const bf16_t* vp = Vt + (size_t)bh * 128 * Nn;   // [d][n]

  const int t = threadIdx.x, wave = t >> 6, lane = t & 63;
  const int quad = lane >> 4, l16 = lane & 15;

  // Q B-frags: lane holds Q[q = qg*16+l16][d = c*32+quad*8+j]
  bf16x8 bq[2][4];
#pragma unroll
  for (int qg = 0; qg < 2; qg++) {
    const size_t qrow = qblk * 64 + wave * 32 + qg * 16 + l16;
#pragma unroll
    for (int c = 0; c < 4; c++)
      bq[qg][c] = *(const bf16x8*)(qp + qrow * 128 + c * 32 + quad * 8);
  }

  // bpermute source-lane indices (bytes): src_quad = (quad&1)*2 + j
  const int idxs[2] = {((((lane >> 4) & 1) * 2 + 0) * 16 + l16) * 4,
                       ((((lane >> 4) & 1) * 2 + 1) * 16 + l16) * 4};
  const bool hi_half = (lane & 32) != 0;  // quad>=2 -> pull from t1

  floatx4 o1[2][8] = {}, o2[2][8] = {};
  float l1a[2] = {0.f, 0.f}, l2a[2] = {0.f, 0.f};

  for (int kt = 0; kt < 16; kt++) {
    const int kb = kt * 64;
#pragma unroll
    for (int c32 = 0; c32 < 2; c32++) {
      int pk[2][2][2][2];  // [t-in-pair][qg][mat][h]
#pragma unroll
      for (int tt = 0; tt < 2; tt++) {
        const int krow = kb + c32 * 32 + tt * 16 + l16;
        bf16x8 ak[4];
#pragma unroll
        for (int c = 0; c < 4; c++)
          ak[c] = *(const bf16x8*)(kp + (size_t)krow * 128 + c * 32 + quad * 8);
#pragma unroll
        for (int qg = 0; qg < 2; qg++) {
          floatx4 s1 = {}, s2 = {};
          s1 = mfma16(ak[0], bq[qg][0], s1);
          s1 = mfma16(ak[1], bq[qg][1], s1);
          s2 = mfma16(ak[2], bq[qg][2], s2);
          s2 = mfma16(ak[3], bq[qg][3], s2);
          float e[4], f[4];
#pragma unroll
          for (int rg = 0; rg < 4; rg++) {
            e[rg] = __builtin_amdgcn_exp2f(s1[rg]);
            f[rg] = __builtin_amdgcn_exp2f(s2[rg]);
          }
          l1a[qg] += (e[0] + e[1]) + (e[2] + e[3]);
          l2a[qg] += (f[0] + f[1]) + (f[2] + f[3]);
          pk[tt][qg][0][0] = pack2bf(e[0], e[1]);
          pk[tt][qg][0][1] = pack2bf(e[2], e[3]);
          pk[tt][qg][1][0] = pack2bf(f[0], f[1]);
          pk[tt][qg][1][1] = pack2bf(f[2], f[3]);
        }
      }
      // C->A transpose via quad permutation
      int aP[2][2][4];
#pragma unroll
      for (int qg = 0; qg < 2; qg++)
#pragma unroll
        for (int mat = 0; mat < 2; mat++)
#pragma unroll
          for (int i = 0; i < 4; i++) {
            const int v0 = __builtin_amdgcn_ds_bpermute(idxs[i >> 1],
                                                        pk[0][qg][mat][i & 1]);
            const int v1 = __builtin_amdgcn_ds_bpermute(idxs[i >> 1],
                                                        pk[1][qg][mat][i & 1]);
            aP[qg][mat][i] = hi_half ? v1 : v0;
          }
      const bf16x8 a10 = as_frag(aP[0][0]), a11 = as_frag(aP[1][0]);
      const bf16x8 a20 = as_frag(aP[0][1]), a21 = as_frag(aP[1][1]);
#pragma unroll
      for (int dt = 0; dt < 8; dt++) {
        const bf16x8 bv = *(const bf16x8*)(vp + (size_t)(dt * 16 + l16) * Nn +
                                           kb + c32 * 32 + quad * 8);
        o1[0][dt] = mfma16(a10, bv, o1[0][dt]);
        o1[1][dt] = mfma16(a11, bv, o1[1][dt]);
        o2[0][dt] = mfma16(a20, bv, o2[0][dt]);
        o2[1][dt] = mfma16(a21, bv, o2[1][dt]);
      }
    }
  }

  // l partials: lane holds sums over its quad's keys for q=l16; reduce quads.
#pragma unroll
  for (int qg = 0; qg < 2; qg++) {
    l1a[qg] += __shfl_xor(l1a[qg], 16); l1a[qg] += __shfl_xor(l1a[qg], 32);
    l2a[qg] += __shfl_xor(l2a[qg], 16); l2a[qg] += __shfl_xor(l2a[qg], 32);
  }

  const float lambda = *lam;
  const int b = bh / Hh, h = bh % Hh;

#pragma unroll
  for (int qg = 0; qg < 2; qg++) {
    float inv1[4], inv2[4];
#pragma unroll
    for (int rg = 0; rg < 4; rg++) {
      const int qr = quad * 4 + rg;  // lane qr holds l for q=qr
      inv1[rg] = 1.0f / __shfl(l1a[qg], qr);
      inv2[rg] = lambda / __shfl(l2a[qg], qr);
    }
    float vals[8][4];
    float sum[4] = {0.f, 0.f, 0.f, 0.f}, ssq[4] = {0.f, 0.f, 0.f, 0.f};
#pragma unroll
    for (int dt = 0; dt < 8; dt++)
#pragma unroll
      for (int rg = 0; rg < 4; rg++) {
        const float v = o1[qg][dt][rg] * inv1[rg] - o2[qg][dt][rg] * inv2[rg];
        vals[dt][rg] = v;
        sum[rg] += v; ssq[rg] += v * v;
      }
#pragma unroll
    for (int m = 8; m >= 1; m >>= 1)
#pragma unroll
      for (int rg = 0; rg < 4; rg++) {
        sum[rg] += __shfl_xor(sum[rg], m);
        ssq[rg] += __shfl_xor(ssq[rg], m);
      }
#pragma unroll
    for (int rg = 0; rg < 4; rg++) {
      const float mu  = sum[rg] * (1.0f / 128.0f);
      const float inv = rsqrtf(ssq[rg] * (1.0f / 128.0f) - mu * mu + EPS_);
      const int n = qblk * 64 + wave * 32 + qg * 16 + quad * 4 + rg;
      bf16_t* orow = outp + ((size_t)(b * Nn + n)) * 1536 + h * 128;
#pragma unroll
      for (int dt = 0; dt < 8; dt++) {
        const int d = dt * 16 + l16;
        orow[d] = (bf16_t)(((vals[dt][rg] - mu) * inv * lnw[d] + lnb[d]) * 0.8f);
      }
    }
  }
}

// ---------------------------------------------------------------------------
extern "C" void kernel_launch(void* const* d_in, const int* in_sizes, int n_in,
                              void* d_out, int out_size, void* d_ws,
                              size_t ws_size, hipStream_t stream) {
  (void)in_sizes; (void)n_in; (void)out_size; (void)ws_size;
  const float* x     = (const float*)d_in[0];
  const float* n1w   = (const float*)d_in[1];
  const float* n1b   = (const float*)d_in[2];
  const float* wq    = (const float*)d_in[3];
  const float* wk    = (const float*)d_in[4];
  const float* wv    = (const float*)d_in[5];
  const float* lam   = (const float*)d_in[6];
  const float* alnw  = (const float*)d_in[7];
  const float* alnb  = (const float*)d_in[8];
  const float* projw = (const float*)d_in[9];
  const float* projb = (const float*)d_in[10];
  const float* n2w   = (const float*)d_in[11];
  const float* n2b   = (const float*)d_in[12];
  const float* fc1w  = (const float*)d_in[13];
  const float* fc1b  = (const float*)d_in[14];
  const float* fc2w  = (const float*)d_in[15];
  const float* fc2b  = (const float*)d_in[16];
  float* out = (float*)d_out;

  char* p = (char*)d_ws;
  bf16_t* xn    = (bf16_t*)p; p += (size_t)Rr * Cc * 2;       // 6.3 MB
  bf16_t* wbuf  = (bf16_t*)p; p += (size_t)9437184 * 2;       // 18.9 MB
  bf16_t* qkv   = (bf16_t*)p; p += (size_t)3 * Rr * 1536 * 2; // 37.7 MB
  bf16_t* attnb = (bf16_t*)p; p += (size_t)Rr * 1536 * 2;     // 12.6 MB
  float*  xmid  = (float*)p;  p += (size_t)Rr * Cc * 4;       // 12.6 MB
  bf16_t* xn2   = (bf16_t*)p; p += (size_t)Rr * Cc * 2;       // 6.3 MB
  bf16_t* hb    = (bf16_t*)p; p += (size_t)Rr * 3072 * 2;     // 25.2 MB

  bf16_t* wqkv_b = wbuf;                 // rows 0..4607 (wq|wk|wv), K=768
  bf16_t* wpj_b  = wbuf + 3538944;
  bf16_t* wf1_b  = wbuf + 4718592;
  bf16_t* wf2_b  = wbuf + 7077888;

  convert_weights<<<9216, 256, 0, stream>>>(wq, wk, wv, projw, fc1w, fc2w, wbuf);
  ln_kernel<<<Rr, 256, 0, stream>>>(x, n1w, n1b, xn);

  gemm_kernel<0><<<dim3(36, 32), 256, 0, stream>>>(xn, wqkv_b, 768, 4608,
                                                   nullptr, qkv);

  const bf16_t* qb  = qkv;
  const bf16_t* kb  = qkv + (size_t)Rr * 1536;
  const bf16_t* vtb = qkv + (size_t)2 * Rr * 1536;
  attn_kernel<<<dim3(48, 16), 128, 0, stream>>>(qb, kb, vtb, lam, alnw, alnb,
                                                attnb);

  gemm64_kernel<<<dim3(6, 64), 256, 0, stream>>>(attnb, wpj_b, 1536, 768,
                                                 projb, x, xmid);
  ln_kernel<<<Rr, 256, 0, stream>>>(xmid, n2w, n2b, xn2);
  gemm_kernel<3><<<dim3(24, 32), 256, 0, stream>>>(xn2, wf1_b, 768, 3072,
                                                   fc1b, hb);
  gemm64_kernel<<<dim3(6, 64), 256, 0, stream>>>(hb, wf2_b, 3072, 768,
                                                 fc2b, xmid, out);
}

// Round 4
// 385.414 us; speedup vs baseline: 1.3039x; 1.3039x over previous
//
#include <hip/hip_runtime.h>
#include <math.h>

// ---------------------------------------------------------------------------
// DiffTransformer encoder layer, MI355X bf16 MFMA. Round 4:
//  - attention: reverted to the round-2 design (S^T + LDS P roundtrip),
//    which measured 91.5 us; the LDS-free round-3 variant spilled ~330 MB
//    to scratch (WRITE_SIZE counter) and regressed 2x.
//  - GEMMs: BK=64 staging -> half the barrier pairs per K (the m97-style
//    vmcnt(0)+s_barrier drain is the known ~20% stall), LDS still 32 KB.
// B=4 N=1024 C=768 H=12 D=64 (2D=128). LAMBDA_INIT=0.2.
// ---------------------------------------------------------------------------

typedef __bf16 bf16_t;
typedef __attribute__((ext_vector_type(8))) __bf16 bf16x8;
typedef __attribute__((ext_vector_type(4))) __bf16 bf16x4;
typedef __attribute__((ext_vector_type(4))) float  floatx4;

constexpr int Bb = 4, Nn = 1024, Cc = 768, Hh = 12;
constexpr int Rr = Bb * Nn;  // 4096 rows
constexpr float EPS_ = 1e-5f;
// exp(s*0.125) == exp2(s*0.125*log2(e)); folded into wq at convert time.
constexpr float QSCALE_ = 0.125f * 1.4426950408889634f;

__device__ __forceinline__ floatx4 mfma16(bf16x8 a, bf16x8 b, floatx4 c) {
  return __builtin_amdgcn_mfma_f32_16x16x32_bf16(a, b, c, 0, 0, 0);
}

// async global->LDS, 16 B per lane; lane i's data lands at lds + i*16B.
__device__ __forceinline__ void async16(bf16_t* lds, const bf16_t* g) {
  __builtin_amdgcn_global_load_lds(
      (__attribute__((address_space(1))) void*)g,
      (__attribute__((address_space(3))) void*)lds, 16, 0, 0);
}

// ---------------------------------------------------------------------------
// Weights f32 -> bf16, contiguous: wq|wk|wv|proj|fc1|fc2. wq scaled by QSCALE_.
// ---------------------------------------------------------------------------
__global__ __launch_bounds__(256) void convert_weights(
    const float* __restrict__ s0, const float* __restrict__ s1,
    const float* __restrict__ s2, const float* __restrict__ s3,
    const float* __restrict__ s4, const float* __restrict__ s5,
    bf16_t* __restrict__ dst) {
  const size_t e = ((size_t)blockIdx.x * 256 + threadIdx.x) * 4;
  const float* src; size_t off; float sc = 1.0f;
  if      (e < 1179648u) { src = s0; off = e;            sc = QSCALE_; }
  else if (e < 2359296u) { src = s1; off = e - 1179648u; }
  else if (e < 3538944u) { src = s2; off = e - 2359296u; }
  else if (e < 4718592u) { src = s3; off = e - 3538944u; }
  else if (e < 7077888u) { src = s4; off = e - 4718592u; }
  else                   { src = s5; off = e - 7077888u; }
  const float4 f = *(const float4*)(src + off);
  bf16x4 o;
  o[0] = (__bf16)(f.x * sc); o[1] = (__bf16)(f.y * sc);
  o[2] = (__bf16)(f.z * sc); o[3] = (__bf16)(f.w * sc);
  *(bf16x4*)(dst + e) = o;
}

// ---------------------------------------------------------------------------
// Row LayerNorm (row length 768) f32 -> bf16. One block per row.
// ---------------------------------------------------------------------------
__global__ __launch_bounds__(256) void ln_kernel(
    const float* __restrict__ x, const float* __restrict__ w,
    const float* __restrict__ b, bf16_t* __restrict__ out) {
  const int row = blockIdx.x, t = threadIdx.x;
  const float* xr = x + (size_t)row * Cc;
  const float v0 = xr[t], v1 = xr[t + 256], v2 = xr[t + 512];
  float s  = v0 + v1 + v2;
  float s2 = v0 * v0 + v1 * v1 + v2 * v2;
#pragma unroll
  for (int off = 32; off > 0; off >>= 1) {
    s  += __shfl_down(s, off);
    s2 += __shfl_down(s2, off);
  }
  __shared__ float ws_[4], ws2_[4];
  if ((t & 63) == 0) { ws_[t >> 6] = s; ws2_[t >> 6] = s2; }
  __syncthreads();
  const float S  = ws_[0] + ws_[1] + ws_[2] + ws_[3];
  const float S2 = ws2_[0] + ws2_[1] + ws2_[2] + ws2_[3];
  const float mu  = S * (1.0f / Cc);
  const float inv = rsqrtf(S2 * (1.0f / Cc) - mu * mu + EPS_);
  bf16_t* orow = out + (size_t)row * Cc;
  orow[t]       = (bf16_t)((v0 - mu) * inv * w[t]       + b[t]);
  orow[t + 256] = (bf16_t)((v1 - mu) * inv * w[t + 256] + b[t + 256]);
  orow[t + 512] = (bf16_t)((v2 - mu) * inv * w[t + 512] + b[t + 512]);
}

// ---------------------------------------------------------------------------
// bf16 MFMA GEMM: 128x128 tile, BK=64 (half the barrier pairs of BK=32),
// unpadded LDS (32 KB), global_load_lds staging (8 instrs/wave per 64-K).
// EPI: 0 = fused qkv scatter, 3 = gelu->bf16.
// ---------------------------------------------------------------------------
template <int EPI>
__global__ __launch_bounds__(256, 3) void gemm_kernel(
    const bf16_t* __restrict__ A, const bf16_t* __restrict__ W,
    int K, int F,
    const float* __restrict__ bias, void* __restrict__ outp) {
  __shared__ alignas(16) bf16_t ldsA[128 * 64];
  __shared__ alignas(16) bf16_t ldsB[128 * 64];
  const int t = threadIdx.x, wave = t >> 6, lane = t & 63;
  const int quad = lane >> 4, l16 = lane & 15;
  const int wm = (wave & 1) * 64, wn = (wave >> 1) * 64;
  const int f0 = blockIdx.x * 128, r0 = blockIdx.y * 128;
  const int srow = lane >> 3, scol = (lane & 7) * 8;  // 8 rows x 128B per instr

  const bf16_t* ga = A + (size_t)(r0 + wave * 32 + srow) * K + scol;
  const bf16_t* gb = W + (size_t)(f0 + wave * 32 + srow) * K + scol;
  bf16_t* la = &ldsA[(wave * 32) * 64];
  bf16_t* lb = &ldsB[(wave * 32) * 64];

  floatx4 acc[4][4] = {};

  for (int k0 = 0; k0 < K; k0 += 64) {
    __syncthreads();
#pragma unroll
    for (int j = 0; j < 4; j++) {
      async16(la + j * 512, ga + k0 + (size_t)(8 * j) * K);
      async16(lb + j * 512, gb + k0 + (size_t)(8 * j) * K);
    }
    __syncthreads();

#pragma unroll
    for (int ks = 0; ks < 2; ks++) {
      bf16x8 af[4], bfr[4];
#pragma unroll
      for (int mt = 0; mt < 4; mt++)
        af[mt] =
            *(const bf16x8*)&ldsA[(wm + mt * 16 + l16) * 64 + ks * 32 + quad * 8];
#pragma unroll
      for (int nt = 0; nt < 4; nt++)
        bfr[nt] =
            *(const bf16x8*)&ldsB[(wn + nt * 16 + l16) * 64 + ks * 32 + quad * 8];
#pragma unroll
      for (int mt = 0; mt < 4; mt++)
#pragma unroll
        for (int nt = 0; nt < 4; nt++)
          acc[mt][nt] = mfma16(af[mt], bfr[nt], acc[mt][nt]);
    }
  }

#pragma unroll
  for (int mt = 0; mt < 4; mt++) {
#pragma unroll
    for (int nt = 0; nt < 4; nt++) {
#pragma unroll
      for (int rg = 0; rg < 4; rg++) {
        const int r = r0 + wm + mt * 16 + quad * 4 + rg;
        const int f = f0 + wn + nt * 16 + l16;
        const float v = acc[mt][nt][rg];
        if constexpr (EPI == 0) {
          const int b = r >> 10, n = r & 1023;
          bf16_t* qkv = (bf16_t*)outp;
          if (f < 1536) {
            const int h = f >> 7, d = f & 127;
            qkv[(((size_t)(b * Hh + h)) * Nn + n) * 128 + d] = (bf16_t)v;
          } else if (f < 3072) {
            const int f2 = f - 1536, h = f2 >> 7, d = f2 & 127;
            (qkv + (size_t)Rr * 1536)
                [(((size_t)(b * Hh + h)) * Nn + n) * 128 + d] = (bf16_t)v;
          } else {
            const int f2 = f - 3072, h = f2 >> 7, d = f2 & 127;
            (qkv + (size_t)2 * Rr * 1536)
                [(((size_t)(b * Hh + h)) * 128 + d) * Nn + n] = (bf16_t)v;
          }
        } else {
          const float z = v + bias[f];
          const float g = 0.5f * z * (1.0f + erff(z * 0.70710678118f));
          ((bf16_t*)outp)[(size_t)r * F + f] = (bf16_t)g;
        }
      }
    }
  }
}

// ---------------------------------------------------------------------------
// 64x128-tile GEMM for F=768 outputs (proj, fc2): grid (6, 64) = 384 blocks.
// BK=64.  f32 out = acc + bias[f] + resid[r*F+f].
// ---------------------------------------------------------------------------
__global__ __launch_bounds__(256, 4) void gemm64_kernel(
    const bf16_t* __restrict__ A, const bf16_t* __restrict__ W,
    int K, int F,
    const float* __restrict__ bias, const float* __restrict__ resid,
    float* __restrict__ outp) {
  __shared__ alignas(16) bf16_t ldsA[64 * 64];
  __shared__ alignas(16) bf16_t ldsB[128 * 64];
  const int t = threadIdx.x, wave = t >> 6, lane = t & 63;
  const int quad = lane >> 4, l16 = lane & 15;
  const int wm = (wave & 1) * 32, wn = (wave >> 1) * 64;
  const int f0 = blockIdx.x * 128, r0 = blockIdx.y * 64;
  const int srow = lane >> 3, scol = (lane & 7) * 8;

  const bf16_t* ga = A + (size_t)(r0 + wave * 16 + srow) * K + scol;
  const bf16_t* gb = W + (size_t)(f0 + wave * 32 + srow) * K + scol;
  bf16_t* la = &ldsA[(wave * 16) * 64];
  bf16_t* lb = &ldsB[(wave * 32) * 64];

  floatx4 acc[2][4] = {};

  for (int k0 = 0; k0 < K; k0 += 64) {
    __syncthreads();
#pragma unroll
    for (int j = 0; j < 2; j++)
      async16(la + j * 512, ga + k0 + (size_t)(8 * j) * K);
#pragma unroll
    for (int j = 0; j < 4; j++)
      async16(lb + j * 512, gb + k0 + (size_t)(8 * j) * K);
    __syncthreads();

#pragma unroll
    for (int ks = 0; ks < 2; ks++) {
      bf16x8 af[2], bfr[4];
#pragma unroll
      for (int mt = 0; mt < 2; mt++)
        af[mt] =
            *(const bf16x8*)&ldsA[(wm + mt * 16 + l16) * 64 + ks * 32 + quad * 8];
#pragma unroll
      for (int nt = 0; nt < 4; nt++)
        bfr[nt] =
            *(const bf16x8*)&ldsB[(wn + nt * 16 + l16) * 64 + ks * 32 + quad * 8];
#pragma unroll
      for (int mt = 0; mt < 2; mt++)
#pragma unroll
        for (int nt = 0; nt < 4; nt++)
          acc[mt][nt] = mfma16(af[mt], bfr[nt], acc[mt][nt]);
    }
  }

#pragma unroll
  for (int mt = 0; mt < 2; mt++)
#pragma unroll
    for (int nt = 0; nt < 4; nt++)
#pragma unroll
      for (int rg = 0; rg < 4; rg++) {
        const int r = r0 + wm + mt * 16 + quad * 4 + rg;
        const int f = f0 + wn + nt * 16 + l16;
        outp[(size_t)r * F + f] =
            acc[mt][nt][rg] + bias[f] + resid[(size_t)r * F + f];
      }
}

// ---------------------------------------------------------------------------
// Differential attention (round-2 design, measured 91.5 us).
// Block = 128 q-rows x 1 head; 4 waves x 32 q.
// S^T formulation: A=K-frag, B=Q-frag => C holds S^T[key=quad*4+rg][q=l16];
// exp2 (Q pre-scaled), pack 4 keys -> ds_write_b64 into P[q][key] (stride 72),
// read back as PV A-frags (b128).  K/V staged with global_load_lds using a
// row-XOR chunk permutation on the GLOBAL side (LDS dest is lane-linear):
//   K [64][128]: 16B slot s of row r holds chunk ((s>>2)^(r&3), s&3)
//   V [128][64]: 16B slot s of row r holds key-slot  s^(r&7)
// No running max: |s*log2e/8| small, exp2 safe in f32; softmax is
// shift-invariant so result is exact.  Epilogue: lambda combine, head-LN,
// *0.8, store to (B,N,1536).
// ---------------------------------------------------------------------------
__global__ __launch_bounds__(256, 2) void attn_kernel(
    const bf16_t* __restrict__ Q, const bf16_t* __restrict__ Kk,
    const bf16_t* __restrict__ Vt, const float* __restrict__ lam,
    const float* __restrict__ lnw, const float* __restrict__ lnb,
    bf16_t* __restrict__ outp) {
  const int qblk = blockIdx.x, bh = blockIdx.y;
  const bf16_t* qp = Q  + (size_t)bh * Nn * 128;   // [n][d]
  const bf16_t* kp = Kk + (size_t)bh * Nn * 128;   // [n][d]
  const bf16_t* vp = Vt + (size_t)bh * 128 * Nn;   // [d][n]

  __shared__ alignas(16) bf16_t ldsK[64 * 128];        // [key][d], swizzled
  __shared__ alignas(16) bf16_t ldsV[128 * 64];        // [d][key], swizzled
  __shared__ alignas(16) bf16_t ldsP[4][2][2][16 * 72];// [wave][mat][qg][q][key]

  const int t = threadIdx.x, wave = t >> 6, lane = t & 63;
  const int quad = lane >> 4, l16 = lane & 15;

  // Q B-frags: lane holds Q[q = qg*16+l16][d = c*32+quad*8+j]
  bf16x8 bq[2][4];
#pragma unroll
  for (int qg = 0; qg < 2; qg++) {
    const size_t qrow = qblk * 128 + wave * 32 + qg * 16 + l16;
#pragma unroll
    for (int c = 0; c < 4; c++)
      bq[qg][c] = *(const bf16x8*)(qp + qrow * 128 + c * 32 + quad * 8);
  }

  // staging addresses (per-lane constants)
  const int ksg = wave * 4;                      // K segs ksg..ksg+3
  const int krl = lane >> 4, kslot = lane & 15;  // 4 rows x 16 slots
  const int vrl = lane >> 3, vslot = lane & 7;   // 8 rows x 8 slots

  floatx4 o1[2][8] = {}, o2[2][8] = {};
  float l1a[2] = {0.f, 0.f}, l2a[2] = {0.f, 0.f};

  for (int kt = 0; kt < 16; kt++) {
    __syncthreads();
#pragma unroll
    for (int j = 0; j < 4; j++) {
      const int seg = ksg + j;
      {  // K: rows seg*4..+3
        const int r = seg * 4 + krl;
        const int cg = (kslot >> 2) ^ (r & 3), ci = kslot & 3;
        async16(&ldsK[seg * 512],
                kp + (size_t)(kt * 64 + r) * 128 + cg * 32 + ci * 8);
      }
      {  // V: rows seg*8..+7
        const int r = seg * 8 + vrl;
        const int sg = vslot ^ (r & 7);
        async16(&ldsV[seg * 512], vp + (size_t)r * Nn + kt * 64 + sg * 8);
      }
    }
    __syncthreads();

    // ---- S^T + exp2 + pack + P write ----
#pragma unroll
    for (int ktile = 0; ktile < 4; ktile++) {
      bf16x8 ak[4];
#pragma unroll
      for (int c = 0; c < 4; c++)
        ak[c] = *(const bf16x8*)&ldsK[(ktile * 16 + l16) * 128 +
                                      ((c ^ (l16 & 3)) * 32) + quad * 8];
#pragma unroll
      for (int qg = 0; qg < 2; qg++) {
        floatx4 s1 = {}, s2 = {};
        s1 = mfma16(ak[0], bq[qg][0], s1);
        s1 = mfma16(ak[1], bq[qg][1], s1);
        s2 = mfma16(ak[2], bq[qg][2], s2);
        s2 = mfma16(ak[3], bq[qg][3], s2);
        bf16x4 p1, p2;
        float a1 = 0.f, a2 = 0.f;
#pragma unroll
        for (int rg = 0; rg < 4; rg++) {
          const float e1 = exp2f(s1[rg]);
          const float e2 = exp2f(s2[rg]);
          p1[rg] = (__bf16)e1; p2[rg] = (__bf16)e2;
          a1 += (float)p1[rg]; a2 += (float)p2[rg];
        }
        l1a[qg] += a1; l2a[qg] += a2;
        const int po = l16 * 72 + ktile * 16 + quad * 4;
        *(bf16x4*)&ldsP[wave][0][qg][po] = p1;
        *(bf16x4*)&ldsP[wave][1][qg][po] = p2;
      }
    }

    // ---- PV ----  (P is wave-private; DS pipe orders the RAW per wave)
    bf16x8 ap1[2][2], ap2[2][2];
#pragma unroll
    for (int qg = 0; qg < 2; qg++)
#pragma unroll
      for (int c = 0; c < 2; c++) {
        const int po = l16 * 72 + c * 32 + quad * 8;
        ap1[qg][c] = *(const bf16x8*)&ldsP[wave][0][qg][po];
        ap2[qg][c] = *(const bf16x8*)&ldsP[wave][1][qg][po];
      }
#pragma unroll
    for (int dt = 0; dt < 8; dt++) {
      const int r = dt * 16 + l16;
      bf16x8 bv[2];
#pragma unroll
      for (int c = 0; c < 2; c++)
        bv[c] = *(const bf16x8*)&ldsV[r * 64 + (((c * 4 + quad) ^ (r & 7)) * 8)];
#pragma unroll
      for (int qg = 0; qg < 2; qg++) {
        o1[qg][dt] = mfma16(ap1[qg][0], bv[0], o1[qg][dt]);
        o1[qg][dt] = mfma16(ap1[qg][1], bv[1], o1[qg][dt]);
        o2[qg][dt] = mfma16(ap2[qg][0], bv[0], o2[qg][dt]);
        o2[qg][dt] = mfma16(ap2[qg][1], bv[1], o2[qg][dt]);
      }
    }
  }

  // l sums: lane holds partials for query (qg, l16) over its quad's keys.
#pragma unroll
  for (int qg = 0; qg < 2; qg++) {
    l1a[qg] += __shfl_xor(l1a[qg], 16); l1a[qg] += __shfl_xor(l1a[qg], 32);
    l2a[qg] += __shfl_xor(l2a[qg], 16); l2a[qg] += __shfl_xor(l2a[qg], 32);
  }

  const float lambda = *lam;
  const int b = bh / Hh, h = bh % Hh;

#pragma unroll
  for (int qg = 0; qg < 2; qg++) {
    // redistribute l: lane needs query row quad*4+rg (value lives in lane qr)
    float inv1[4], inv2[4];
#pragma unroll
    for (int rg = 0; rg < 4; rg++) {
      const int qr = quad * 4 + rg;
      inv1[rg] = 1.0f / __shfl(l1a[qg], qr);
      inv2[rg] = lambda / __shfl(l2a[qg], qr);
    }
    float vals[8][4];
    float sum[4] = {0.f, 0.f, 0.f, 0.f}, ssq[4] = {0.f, 0.f, 0.f, 0.f};
#pragma unroll
    for (int dt = 0; dt < 8; dt++)
#pragma unroll
      for (int rg = 0; rg < 4; rg++) {
        const float v = o1[qg][dt][rg] * inv1[rg] - o2[qg][dt][rg] * inv2[rg];
        vals[dt][rg] = v;
        sum[rg] += v; ssq[rg] += v * v;
      }
#pragma unroll
    for (int m = 8; m >= 1; m >>= 1)
#pragma unroll
      for (int rg = 0; rg < 4; rg++) {
        sum[rg] += __shfl_xor(sum[rg], m);
        ssq[rg] += __shfl_xor(ssq[rg], m);
      }
#pragma unroll
    for (int rg = 0; rg < 4; rg++) {
      const float mu  = sum[rg] * (1.0f / 128.0f);
      const float inv = rsqrtf(ssq[rg] * (1.0f / 128.0f) - mu * mu + EPS_);
      const int n = qblk * 128 + wave * 32 + qg * 16 + quad * 4 + rg;
      bf16_t* orow = outp + ((size_t)(b * Nn + n)) * 1536 + h * 128;
#pragma unroll
      for (int dt = 0; dt < 8; dt++) {
        const int d = dt * 16 + l16;
        orow[d] = (bf16_t)(((vals[dt][rg] - mu) * inv * lnw[d] + lnb[d]) * 0.8f);
      }
    }
  }
}

// ---------------------------------------------------------------------------
extern "C" void kernel_launch(void* const* d_in, const int* in_sizes, int n_in,
                              void* d_out, int out_size, void* d_ws,
                              size_t ws_size, hipStream_t stream) {
  (void)in_sizes; (void)n_in; (void)out_size; (void)ws_size;
  const float* x     = (const float*)d_in[0];
  const float* n1w   = (const float*)d_in[1];
  const float* n1b   = (const float*)d_in[2];
  const float* wq    = (const float*)d_in[3];
  const float* wk    = (const float*)d_in[4];
  const float* wv    = (const float*)d_in[5];
  const float* lam   = (const float*)d_in[6];
  const float* alnw  = (const float*)d_in[7];
  const float* alnb  = (const float*)d_in[8];
  const float* projw = (const float*)d_in[9];
  const float* projb = (const float*)d_in[10];
  const float* n2w   = (const float*)d_in[11];
  const float* n2b   = (const float*)d_in[12];
  const float* fc1w  = (const float*)d_in[13];
  const float* fc1b  = (const float*)d_in[14];
  const float* fc2w  = (const float*)d_in[15];
  const float* fc2b  = (const float*)d_in[16];
  float* out = (float*)d_out;

  char* p = (char*)d_ws;
  bf16_t* xn    = (bf16_t*)p; p += (size_t)Rr * Cc * 2;       // 6.3 MB
  bf16_t* wbuf  = (bf16_t*)p; p += (size_t)9437184 * 2;       // 18.9 MB
  bf16_t* qkv   = (bf16_t*)p; p += (size_t)3 * Rr * 1536 * 2; // 37.7 MB
  bf16_t* attnb = (bf16_t*)p; p += (size_t)Rr * 1536 * 2;     // 12.6 MB
  float*  xmid  = (float*)p;  p += (size_t)Rr * Cc * 4;       // 12.6 MB
  bf16_t* xn2   = (bf16_t*)p; p += (size_t)Rr * Cc * 2;       // 6.3 MB
  bf16_t* hb    = (bf16_t*)p; p += (size_t)Rr * 3072 * 2;     // 25.2 MB

  bf16_t* wqkv_b = wbuf;                 // rows 0..4607 (wq|wk|wv), K=768
  bf16_t* wpj_b  = wbuf + 3538944;
  bf16_t* wf1_b  = wbuf + 4718592;
  bf16_t* wf2_b  = wbuf + 7077888;

  convert_weights<<<9216, 256, 0, stream>>>(wq, wk, wv, projw, fc1w, fc2w, wbuf);
  ln_kernel<<<Rr, 256, 0, stream>>>(x, n1w, n1b, xn);

  gemm_kernel<0><<<dim3(36, 32), 256, 0, stream>>>(xn, wqkv_b, 768, 4608,
                                                   nullptr, qkv);

  const bf16_t* qb  = qkv;
  const bf16_t* kb  = qkv + (size_t)Rr * 1536;
  const bf16_t* vtb = qkv + (size_t)2 * Rr * 1536;
  attn_kernel<<<dim3(8, 48), 256, 0, stream>>>(qb, kb, vtb, lam, alnw, alnb,
                                               attnb);

  gemm64_kernel<<<dim3(6, 64), 256, 0, stream>>>(attnb, wpj_b, 1536, 768,
                                                 projb, x, xmid);
  ln_kernel<<<Rr, 256, 0, stream>>>(xmid, n2w, n2b, xn2);
  gemm_kernel<3><<<dim3(24, 32), 256, 0, stream>>>(xn2, wf1_b, 768, 3072,
                                                   fc1b, hb);
  gemm64_kernel<<<dim3(6, 64), 256, 0, stream>>>(hb, wf2_b, 3072, 768,
                                                 fc2b, xmid, out);
}

// Round 5
// 367.638 us; speedup vs baseline: 1.3670x; 1.0484x over previous
//
#include <hip/hip_runtime.h>
#include <math.h>

// ---------------------------------------------------------------------------
// DiffTransformer encoder layer, MI355X bf16 MFMA. Round 5:
//  - attention grid swapped to (48 bh, 8 qblk): 48 % 8 == 0 pins every
//    q-block of head h to XCD h%8 -> K/V (512 KB/head, 3 MB/XCD) stays
//    L2-resident.  R4 counters showed FETCH 104.5 MB vs 37.8 ideal = the
//    old x=qblk mapping scattered same-head blocks across XCDs.
//  - exp2f -> __builtin_amdgcn_exp2f (raw v_exp_f32; args bounded).
//  - GEMMs unchanged (BK=64, global_load_lds).
// B=4 N=1024 C=768 H=12 D=64 (2D=128). LAMBDA_INIT=0.2.
// ---------------------------------------------------------------------------

typedef __bf16 bf16_t;
typedef __attribute__((ext_vector_type(8))) __bf16 bf16x8;
typedef __attribute__((ext_vector_type(4))) __bf16 bf16x4;
typedef __attribute__((ext_vector_type(4))) float  floatx4;

constexpr int Bb = 4, Nn = 1024, Cc = 768, Hh = 12;
constexpr int Rr = Bb * Nn;  // 4096 rows
constexpr float EPS_ = 1e-5f;
// exp(s*0.125) == exp2(s*0.125*log2(e)); folded into wq at convert time.
constexpr float QSCALE_ = 0.125f * 1.4426950408889634f;

__device__ __forceinline__ floatx4 mfma16(bf16x8 a, bf16x8 b, floatx4 c) {
  return __builtin_amdgcn_mfma_f32_16x16x32_bf16(a, b, c, 0, 0, 0);
}

// async global->LDS, 16 B per lane; lane i's data lands at lds + i*16B.
__device__ __forceinline__ void async16(bf16_t* lds, const bf16_t* g) {
  __builtin_amdgcn_global_load_lds(
      (__attribute__((address_space(1))) void*)g,
      (__attribute__((address_space(3))) void*)lds, 16, 0, 0);
}

// ---------------------------------------------------------------------------
// Weights f32 -> bf16, contiguous: wq|wk|wv|proj|fc1|fc2. wq scaled by QSCALE_.
// ---------------------------------------------------------------------------
__global__ __launch_bounds__(256) void convert_weights(
    const float* __restrict__ s0, const float* __restrict__ s1,
    const float* __restrict__ s2, const float* __restrict__ s3,
    const float* __restrict__ s4, const float* __restrict__ s5,
    bf16_t* __restrict__ dst) {
  const size_t e = ((size_t)blockIdx.x * 256 + threadIdx.x) * 4;
  const float* src; size_t off; float sc = 1.0f;
  if      (e < 1179648u) { src = s0; off = e;            sc = QSCALE_; }
  else if (e < 2359296u) { src = s1; off = e - 1179648u; }
  else if (e < 3538944u) { src = s2; off = e - 2359296u; }
  else if (e < 4718592u) { src = s3; off = e - 3538944u; }
  else if (e < 7077888u) { src = s4; off = e - 4718592u; }
  else                   { src = s5; off = e - 7077888u; }
  const float4 f = *(const float4*)(src + off);
  bf16x4 o;
  o[0] = (__bf16)(f.x * sc); o[1] = (__bf16)(f.y * sc);
  o[2] = (__bf16)(f.z * sc); o[3] = (__bf16)(f.w * sc);
  *(bf16x4*)(dst + e) = o;
}

// ---------------------------------------------------------------------------
// Row LayerNorm (row length 768) f32 -> bf16. One block per row.
// ---------------------------------------------------------------------------
__global__ __launch_bounds__(256) void ln_kernel(
    const float* __restrict__ x, const float* __restrict__ w,
    const float* __restrict__ b, bf16_t* __restrict__ out) {
  const int row = blockIdx.x, t = threadIdx.x;
  const float* xr = x + (size_t)row * Cc;
  const float v0 = xr[t], v1 = xr[t + 256], v2 = xr[t + 512];
  float s  = v0 + v1 + v2;
  float s2 = v0 * v0 + v1 * v1 + v2 * v2;
#pragma unroll
  for (int off = 32; off > 0; off >>= 1) {
    s  += __shfl_down(s, off);
    s2 += __shfl_down(s2, off);
  }
  __shared__ float ws_[4], ws2_[4];
  if ((t & 63) == 0) { ws_[t >> 6] = s; ws2_[t >> 6] = s2; }
  __syncthreads();
  const float S  = ws_[0] + ws_[1] + ws_[2] + ws_[3];
  const float S2 = ws2_[0] + ws2_[1] + ws2_[2] + ws2_[3];
  const float mu  = S * (1.0f / Cc);
  const float inv = rsqrtf(S2 * (1.0f / Cc) - mu * mu + EPS_);
  bf16_t* orow = out + (size_t)row * Cc;
  orow[t]       = (bf16_t)((v0 - mu) * inv * w[t]       + b[t]);
  orow[t + 256] = (bf16_t)((v1 - mu) * inv * w[t + 256] + b[t + 256]);
  orow[t + 512] = (bf16_t)((v2 - mu) * inv * w[t + 512] + b[t + 512]);
}

// ---------------------------------------------------------------------------
// bf16 MFMA GEMM: 128x128 tile, BK=64, unpadded LDS (32 KB),
// global_load_lds staging.  EPI: 0 = fused qkv scatter, 3 = gelu->bf16.
// ---------------------------------------------------------------------------
template <int EPI>
__global__ __launch_bounds__(256, 3) void gemm_kernel(
    const bf16_t* __restrict__ A, const bf16_t* __restrict__ W,
    int K, int F,
    const float* __restrict__ bias, void* __restrict__ outp) {
  __shared__ alignas(16) bf16_t ldsA[128 * 64];
  __shared__ alignas(16) bf16_t ldsB[128 * 64];
  const int t = threadIdx.x, wave = t >> 6, lane = t & 63;
  const int quad = lane >> 4, l16 = lane & 15;
  const int wm = (wave & 1) * 64, wn = (wave >> 1) * 64;
  const int f0 = blockIdx.x * 128, r0 = blockIdx.y * 128;
  const int srow = lane >> 3, scol = (lane & 7) * 8;  // 8 rows x 128B per instr

  const bf16_t* ga = A + (size_t)(r0 + wave * 32 + srow) * K + scol;
  const bf16_t* gb = W + (size_t)(f0 + wave * 32 + srow) * K + scol;
  bf16_t* la = &ldsA[(wave * 32) * 64];
  bf16_t* lb = &ldsB[(wave * 32) * 64];

  floatx4 acc[4][4] = {};

  for (int k0 = 0; k0 < K; k0 += 64) {
    __syncthreads();
#pragma unroll
    for (int j = 0; j < 4; j++) {
      async16(la + j * 512, ga + k0 + (size_t)(8 * j) * K);
      async16(lb + j * 512, gb + k0 + (size_t)(8 * j) * K);
    }
    __syncthreads();

#pragma unroll
    for (int ks = 0; ks < 2; ks++) {
      bf16x8 af[4], bfr[4];
#pragma unroll
      for (int mt = 0; mt < 4; mt++)
        af[mt] =
            *(const bf16x8*)&ldsA[(wm + mt * 16 + l16) * 64 + ks * 32 + quad * 8];
#pragma unroll
      for (int nt = 0; nt < 4; nt++)
        bfr[nt] =
            *(const bf16x8*)&ldsB[(wn + nt * 16 + l16) * 64 + ks * 32 + quad * 8];
#pragma unroll
      for (int mt = 0; mt < 4; mt++)
#pragma unroll
        for (int nt = 0; nt < 4; nt++)
          acc[mt][nt] = mfma16(af[mt], bfr[nt], acc[mt][nt]);
    }
  }

#pragma unroll
  for (int mt = 0; mt < 4; mt++) {
#pragma unroll
    for (int nt = 0; nt < 4; nt++) {
#pragma unroll
      for (int rg = 0; rg < 4; rg++) {
        const int r = r0 + wm + mt * 16 + quad * 4 + rg;
        const int f = f0 + wn + nt * 16 + l16;
        const float v = acc[mt][nt][rg];
        if constexpr (EPI == 0) {
          const int b = r >> 10, n = r & 1023;
          bf16_t* qkv = (bf16_t*)outp;
          if (f < 1536) {
            const int h = f >> 7, d = f & 127;
            qkv[(((size_t)(b * Hh + h)) * Nn + n) * 128 + d] = (bf16_t)v;
          } else if (f < 3072) {
            const int f2 = f - 1536, h = f2 >> 7, d = f2 & 127;
            (qkv + (size_t)Rr * 1536)
                [(((size_t)(b * Hh + h)) * Nn + n) * 128 + d] = (bf16_t)v;
          } else {
            const int f2 = f - 3072, h = f2 >> 7, d = f2 & 127;
            (qkv + (size_t)2 * Rr * 1536)
                [(((size_t)(b * Hh + h)) * 128 + d) * Nn + n] = (bf16_t)v;
          }
        } else {
          const float z = v + bias[f];
          const float g = 0.5f * z * (1.0f + erff(z * 0.70710678118f));
          ((bf16_t*)outp)[(size_t)r * F + f] = (bf16_t)g;
        }
      }
    }
  }
}

// ---------------------------------------------------------------------------
// 64x128-tile GEMM for F=768 outputs (proj, fc2): grid (6, 64) = 384 blocks.
// BK=64.  f32 out = acc + bias[f] + resid[r*F+f].
// ---------------------------------------------------------------------------
__global__ __launch_bounds__(256, 4) void gemm64_kernel(
    const bf16_t* __restrict__ A, const bf16_t* __restrict__ W,
    int K, int F,
    const float* __restrict__ bias, const float* __restrict__ resid,
    float* __restrict__ outp) {
  __shared__ alignas(16) bf16_t ldsA[64 * 64];
  __shared__ alignas(16) bf16_t ldsB[128 * 64];
  const int t = threadIdx.x, wave = t >> 6, lane = t & 63;
  const int quad = lane >> 4, l16 = lane & 15;
  const int wm = (wave & 1) * 32, wn = (wave >> 1) * 64;
  const int f0 = blockIdx.x * 128, r0 = blockIdx.y * 64;
  const int srow = lane >> 3, scol = (lane & 7) * 8;

  const bf16_t* ga = A + (size_t)(r0 + wave * 16 + srow) * K + scol;
  const bf16_t* gb = W + (size_t)(f0 + wave * 32 + srow) * K + scol;
  bf16_t* la = &ldsA[(wave * 16) * 64];
  bf16_t* lb = &ldsB[(wave * 32) * 64];

  floatx4 acc[2][4] = {};

  for (int k0 = 0; k0 < K; k0 += 64) {
    __syncthreads();
#pragma unroll
    for (int j = 0; j < 2; j++)
      async16(la + j * 512, ga + k0 + (size_t)(8 * j) * K);
#pragma unroll
    for (int j = 0; j < 4; j++)
      async16(lb + j * 512, gb + k0 + (size_t)(8 * j) * K);
    __syncthreads();

#pragma unroll
    for (int ks = 0; ks < 2; ks++) {
      bf16x8 af[2], bfr[4];
#pragma unroll
      for (int mt = 0; mt < 2; mt++)
        af[mt] =
            *(const bf16x8*)&ldsA[(wm + mt * 16 + l16) * 64 + ks * 32 + quad * 8];
#pragma unroll
      for (int nt = 0; nt < 4; nt++)
        bfr[nt] =
            *(const bf16x8*)&ldsB[(wn + nt * 16 + l16) * 64 + ks * 32 + quad * 8];
#pragma unroll
      for (int mt = 0; mt < 2; mt++)
#pragma unroll
        for (int nt = 0; nt < 4; nt++)
          acc[mt][nt] = mfma16(af[mt], bfr[nt], acc[mt][nt]);
    }
  }

#pragma unroll
  for (int mt = 0; mt < 2; mt++)
#pragma unroll
    for (int nt = 0; nt < 4; nt++)
#pragma unroll
      for (int rg = 0; rg < 4; rg++) {
        const int r = r0 + wm + mt * 16 + quad * 4 + rg;
        const int f = f0 + wn + nt * 16 + l16;
        outp[(size_t)r * F + f] =
            acc[mt][nt][rg] + bias[f] + resid[(size_t)r * F + f];
      }
}

// ---------------------------------------------------------------------------
// Differential attention (round-2 structure; grid now head-major).
// Block = 128 q-rows x 1 head; 4 waves x 32 q.  grid (48 bh, 8 qblk):
// head h -> XCD h%8 for every q-block (48 % 8 == 0), so K/V stay L2-resident.
// S^T formulation: A=K-frag, B=Q-frag => C holds S^T[key=quad*4+rg][q=l16];
// exp2 (Q pre-scaled), pack 4 keys -> ds_write_b64 into P[q][key] (stride 72),
// read back as PV A-frags (b128).  K/V staged with global_load_lds using a
// row-XOR chunk permutation on the GLOBAL side (LDS dest is lane-linear):
//   K [64][128]: 16B slot s of row r holds chunk ((s>>2)^(r&3), s&3)
//   V [128][64]: 16B slot s of row r holds key-slot  s^(r&7)
// No running max: |s*log2e/8| small, exp2 safe in f32; softmax is
// shift-invariant so result is exact.  Epilogue: lambda combine, head-LN,
// *0.8, store to (B,N,1536).
// ---------------------------------------------------------------------------
__global__ __launch_bounds__(256, 2) void attn_kernel(
    const bf16_t* __restrict__ Q, const bf16_t* __restrict__ Kk,
    const bf16_t* __restrict__ Vt, const float* __restrict__ lam,
    const float* __restrict__ lnw, const float* __restrict__ lnb,
    bf16_t* __restrict__ outp) {
  const int bh = blockIdx.x, qblk = blockIdx.y;  // head-major: XCD = bh % 8
  const bf16_t* qp = Q  + (size_t)bh * Nn * 128;   // [n][d]
  const bf16_t* kp = Kk + (size_t)bh * Nn * 128;   // [n][d]
  const bf16_t* vp = Vt + (size_t)bh * 128 * Nn;   // [d][n]

  __shared__ alignas(16) bf16_t ldsK[64 * 128];        // [key][d], swizzled
  __shared__ alignas(16) bf16_t ldsV[128 * 64];        // [d][key], swizzled
  __shared__ alignas(16) bf16_t ldsP[4][2][2][16 * 72];// [wave][mat][qg][q][key]

  const int t = threadIdx.x, wave = t >> 6, lane = t & 63;
  const int quad = lane >> 4, l16 = lane & 15;

  // Q B-frags: lane holds Q[q = qg*16+l16][d = c*32+quad*8+j]
  bf16x8 bq[2][4];
#pragma unroll
  for (int qg = 0; qg < 2; qg++) {
    const size_t qrow = qblk * 128 + wave * 32 + qg * 16 + l16;
#pragma unroll
    for (int c = 0; c < 4; c++)
      bq[qg][c] = *(const bf16x8*)(qp + qrow * 128 + c * 32 + quad * 8);
  }

  // staging addresses (per-lane constants)
  const int ksg = wave * 4;                      // K segs ksg..ksg+3
  const int krl = lane >> 4, kslot = lane & 15;  // 4 rows x 16 slots
  const int vrl = lane >> 3, vslot = lane & 7;   // 8 rows x 8 slots

  floatx4 o1[2][8] = {}, o2[2][8] = {};
  float l1a[2] = {0.f, 0.f}, l2a[2] = {0.f, 0.f};

  for (int kt = 0; kt < 16; kt++) {
    __syncthreads();
#pragma unroll
    for (int j = 0; j < 4; j++) {
      const int seg = ksg + j;
      {  // K: rows seg*4..+3
        const int r = seg * 4 + krl;
        const int cg = (kslot >> 2) ^ (r & 3), ci = kslot & 3;
        async16(&ldsK[seg * 512],
                kp + (size_t)(kt * 64 + r) * 128 + cg * 32 + ci * 8);
      }
      {  // V: rows seg*8..+7
        const int r = seg * 8 + vrl;
        const int sg = vslot ^ (r & 7);
        async16(&ldsV[seg * 512], vp + (size_t)r * Nn + kt * 64 + sg * 8);
      }
    }
    __syncthreads();

    // ---- S^T + exp2 + pack + P write ----
#pragma unroll
    for (int ktile = 0; ktile < 4; ktile++) {
      bf16x8 ak[4];
#pragma unroll
      for (int c = 0; c < 4; c++)
        ak[c] = *(const bf16x8*)&ldsK[(ktile * 16 + l16) * 128 +
                                      ((c ^ (l16 & 3)) * 32) + quad * 8];
#pragma unroll
      for (int qg = 0; qg < 2; qg++) {
        floatx4 s1 = {}, s2 = {};
        s1 = mfma16(ak[0], bq[qg][0], s1);
        s1 = mfma16(ak[1], bq[qg][1], s1);
        s2 = mfma16(ak[2], bq[qg][2], s2);
        s2 = mfma16(ak[3], bq[qg][3], s2);
        bf16x4 p1, p2;
        float a1 = 0.f, a2 = 0.f;
#pragma unroll
        for (int rg = 0; rg < 4; rg++) {
          const float e1 = __builtin_amdgcn_exp2f(s1[rg]);
          const float e2 = __builtin_amdgcn_exp2f(s2[rg]);
          p1[rg] = (__bf16)e1; p2[rg] = (__bf16)e2;
          a1 += (float)p1[rg]; a2 += (float)p2[rg];
        }
        l1a[qg] += a1; l2a[qg] += a2;
        const int po = l16 * 72 + ktile * 16 + quad * 4;
        *(bf16x4*)&ldsP[wave][0][qg][po] = p1;
        *(bf16x4*)&ldsP[wave][1][qg][po] = p2;
      }
    }

    // ---- PV ----  (P is wave-private; DS pipe orders the RAW per wave)
    bf16x8 ap1[2][2], ap2[2][2];
#pragma unroll
    for (int qg = 0; qg < 2; qg++)
#pragma unroll
      for (int c = 0; c < 2; c++) {
        const int po = l16 * 72 + c * 32 + quad * 8;
        ap1[qg][c] = *(const bf16x8*)&ldsP[wave][0][qg][po];
        ap2[qg][c] = *(const bf16x8*)&ldsP[wave][1][qg][po];
      }
#pragma unroll
    for (int dt = 0; dt < 8; dt++) {
      const int r = dt * 16 + l16;
      bf16x8 bv[2];
#pragma unroll
      for (int c = 0; c < 2; c++)
        bv[c] = *(const bf16x8*)&ldsV[r * 64 + (((c * 4 + quad) ^ (r & 7)) * 8)];
#pragma unroll
      for (int qg = 0; qg < 2; qg++) {
        o1[qg][dt] = mfma16(ap1[qg][0], bv[0], o1[qg][dt]);
        o1[qg][dt] = mfma16(ap1[qg][1], bv[1], o1[qg][dt]);
        o2[qg][dt] = mfma16(ap2[qg][0], bv[0], o2[qg][dt]);
        o2[qg][dt] = mfma16(ap2[qg][1], bv[1], o2[qg][dt]);
      }
    }
  }

  // l sums: lane holds partials for query (qg, l16) over its quad's keys.
#pragma unroll
  for (int qg = 0; qg < 2; qg++) {
    l1a[qg] += __shfl_xor(l1a[qg], 16); l1a[qg] += __shfl_xor(l1a[qg], 32);
    l2a[qg] += __shfl_xor(l2a[qg], 16); l2a[qg] += __shfl_xor(l2a[qg], 32);
  }

  const float lambda = *lam;
  const int b = bh / Hh, h = bh % Hh;

#pragma unroll
  for (int qg = 0; qg < 2; qg++) {
    // redistribute l: lane needs query row quad*4+rg (value lives in lane qr)
    float inv1[4], inv2[4];
#pragma unroll
    for (int rg = 0; rg < 4; rg++) {
      const int qr = quad * 4 + rg;
      inv1[rg] = 1.0f / __shfl(l1a[qg], qr);
      inv2[rg] = lambda / __shfl(l2a[qg], qr);
    }
    float vals[8][4];
    float sum[4] = {0.f, 0.f, 0.f, 0.f}, ssq[4] = {0.f, 0.f, 0.f, 0.f};
#pragma unroll
    for (int dt = 0; dt < 8; dt++)
#pragma unroll
      for (int rg = 0; rg < 4; rg++) {
        const float v = o1[qg][dt][rg] * inv1[rg] - o2[qg][dt][rg] * inv2[rg];
        vals[dt][rg] = v;
        sum[rg] += v; ssq[rg] += v * v;
      }
#pragma unroll
    for (int m = 8; m >= 1; m >>= 1)
#pragma unroll
      for (int rg = 0; rg < 4; rg++) {
        sum[rg] += __shfl_xor(sum[rg], m);
        ssq[rg] += __shfl_xor(ssq[rg], m);
      }
#pragma unroll
    for (int rg = 0; rg < 4; rg++) {
      const float mu  = sum[rg] * (1.0f / 128.0f);
      const float inv = rsqrtf(ssq[rg] * (1.0f / 128.0f) - mu * mu + EPS_);
      const int n = qblk * 128 + wave * 32 + qg * 16 + quad * 4 + rg;
      bf16_t* orow = outp + ((size_t)(b * Nn + n)) * 1536 + h * 128;
#pragma unroll
      for (int dt = 0; dt < 8; dt++) {
        const int d = dt * 16 + l16;
        orow[d] = (bf16_t)(((vals[dt][rg] - mu) * inv * lnw[d] + lnb[d]) * 0.8f);
      }
    }
  }
}

// ---------------------------------------------------------------------------
extern "C" void kernel_launch(void* const* d_in, const int* in_sizes, int n_in,
                              void* d_out, int out_size, void* d_ws,
                              size_t ws_size, hipStream_t stream) {
  (void)in_sizes; (void)n_in; (void)out_size; (void)ws_size;
  const float* x     = (const float*)d_in[0];
  const float* n1w   = (const float*)d_in[1];
  const float* n1b   = (const float*)d_in[2];
  const float* wq    = (const float*)d_in[3];
  const float* wk    = (const float*)d_in[4];
  const float* wv    = (const float*)d_in[5];
  const float* lam   = (const float*)d_in[6];
  const float* alnw  = (const float*)d_in[7];
  const float* alnb  = (const float*)d_in[8];
  const float* projw = (const float*)d_in[9];
  const float* projb = (const float*)d_in[10];
  const float* n2w   = (const float*)d_in[11];
  const float* n2b   = (const float*)d_in[12];
  const float* fc1w  = (const float*)d_in[13];
  const float* fc1b  = (const float*)d_in[14];
  const float* fc2w  = (const float*)d_in[15];
  const float* fc2b  = (const float*)d_in[16];
  float* out = (float*)d_out;

  char* p = (char*)d_ws;
  bf16_t* xn    = (bf16_t*)p; p += (size_t)Rr * Cc * 2;       // 6.3 MB
  bf16_t* wbuf  = (bf16_t*)p; p += (size_t)9437184 * 2;       // 18.9 MB
  bf16_t* qkv   = (bf16_t*)p; p += (size_t)3 * Rr * 1536 * 2; // 37.7 MB
  bf16_t* attnb = (bf16_t*)p; p += (size_t)Rr * 1536 * 2;     // 12.6 MB
  float*  xmid  = (float*)p;  p += (size_t)Rr * Cc * 4;       // 12.6 MB
  bf16_t* xn2   = (bf16_t*)p; p += (size_t)Rr * Cc * 2;       // 6.3 MB
  bf16_t* hb    = (bf16_t*)p; p += (size_t)Rr * 3072 * 2;     // 25.2 MB

  bf16_t* wqkv_b = wbuf;                 // rows 0..4607 (wq|wk|wv), K=768
  bf16_t* wpj_b  = wbuf + 3538944;
  bf16_t* wf1_b  = wbuf + 4718592;
  bf16_t* wf2_b  = wbuf + 7077888;

  convert_weights<<<9216, 256, 0, stream>>>(wq, wk, wv, projw, fc1w, fc2w, wbuf);
  ln_kernel<<<Rr, 256, 0, stream>>>(x, n1w, n1b, xn);

  gemm_kernel<0><<<dim3(36, 32), 256, 0, stream>>>(xn, wqkv_b, 768, 4608,
                                                   nullptr, qkv);

  const bf16_t* qb  = qkv;
  const bf16_t* kb  = qkv + (size_t)Rr * 1536;
  const bf16_t* vtb = qkv + (size_t)2 * Rr * 1536;
  attn_kernel<<<dim3(48, 8), 256, 0, stream>>>(qb, kb, vtb, lam, alnw, alnb,
                                               attnb);

  gemm64_kernel<<<dim3(6, 64), 256, 0, stream>>>(attnb, wpj_b, 1536, 768,
                                                 projb, x, xmid);
  ln_kernel<<<Rr, 256, 0, stream>>>(xmid, n2w, n2b, xn2);
  gemm_kernel<3><<<dim3(24, 32), 256, 0, stream>>>(xn2, wf1_b, 768, 3072,
                                                   fc1b, hb);
  gemm64_kernel<<<dim3(6, 64), 256, 0, stream>>>(hb, wf2_b, 3072, 768,
                                                 fc2b, xmid, out);
}

// Round 6
// 348.211 us; speedup vs baseline: 1.4432x; 1.0558x over previous
//
#include <hip/hip_runtime.h>
#include <math.h>

// ---------------------------------------------------------------------------
// DiffTransformer encoder layer, MI355X bf16 MFMA. Round 6:
//  - GEMM LDS bank-conflict fix: BK=64 row stride (128 B) aliases all 16
//    lanes of a ds_read_b128 group onto one 4-bank group (R5 counter:
//    1.06e7 conflicts on qkv).  XOR-swizzle chunk slot with row&7 on the
//    global source side (global_load_lds dest is lane-linear); frag reads
//    use slot (ks*4+quad)^(l16&7) -> 8-cycle floor.
//  - attention unchanged from R5 (71.5 us, FETCH 18.7 MB, head-major grid).
// B=4 N=1024 C=768 H=12 D=64 (2D=128). LAMBDA_INIT=0.2.
// ---------------------------------------------------------------------------

typedef __bf16 bf16_t;
typedef __attribute__((ext_vector_type(8))) __bf16 bf16x8;
typedef __attribute__((ext_vector_type(4))) __bf16 bf16x4;
typedef __attribute__((ext_vector_type(4))) float  floatx4;

constexpr int Bb = 4, Nn = 1024, Cc = 768, Hh = 12;
constexpr int Rr = Bb * Nn;  // 4096 rows
constexpr float EPS_ = 1e-5f;
// exp(s*0.125) == exp2(s*0.125*log2(e)); folded into wq at convert time.
constexpr float QSCALE_ = 0.125f * 1.4426950408889634f;

__device__ __forceinline__ floatx4 mfma16(bf16x8 a, bf16x8 b, floatx4 c) {
  return __builtin_amdgcn_mfma_f32_16x16x32_bf16(a, b, c, 0, 0, 0);
}

// async global->LDS, 16 B per lane; lane i's data lands at lds + i*16B.
__device__ __forceinline__ void async16(bf16_t* lds, const bf16_t* g) {
  __builtin_amdgcn_global_load_lds(
      (__attribute__((address_space(1))) void*)g,
      (__attribute__((address_space(3))) void*)lds, 16, 0, 0);
}

// ---------------------------------------------------------------------------
// Weights f32 -> bf16, contiguous: wq|wk|wv|proj|fc1|fc2. wq scaled by QSCALE_.
// ---------------------------------------------------------------------------
__global__ __launch_bounds__(256) void convert_weights(
    const float* __restrict__ s0, const float* __restrict__ s1,
    const float* __restrict__ s2, const float* __restrict__ s3,
    const float* __restrict__ s4, const float* __restrict__ s5,
    bf16_t* __restrict__ dst) {
  const size_t e = ((size_t)blockIdx.x * 256 + threadIdx.x) * 4;
  const float* src; size_t off; float sc = 1.0f;
  if      (e < 1179648u) { src = s0; off = e;            sc = QSCALE_; }
  else if (e < 2359296u) { src = s1; off = e - 1179648u; }
  else if (e < 3538944u) { src = s2; off = e - 2359296u; }
  else if (e < 4718592u) { src = s3; off = e - 3538944u; }
  else if (e < 7077888u) { src = s4; off = e - 4718592u; }
  else                   { src = s5; off = e - 7077888u; }
  const float4 f = *(const float4*)(src + off);
  bf16x4 o;
  o[0] = (__bf16)(f.x * sc); o[1] = (__bf16)(f.y * sc);
  o[2] = (__bf16)(f.z * sc); o[3] = (__bf16)(f.w * sc);
  *(bf16x4*)(dst + e) = o;
}

// ---------------------------------------------------------------------------
// Row LayerNorm (row length 768) f32 -> bf16. One block per row.
// ---------------------------------------------------------------------------
__global__ __launch_bounds__(256) void ln_kernel(
    const float* __restrict__ x, const float* __restrict__ w,
    const float* __restrict__ b, bf16_t* __restrict__ out) {
  const int row = blockIdx.x, t = threadIdx.x;
  const float* xr = x + (size_t)row * Cc;
  const float v0 = xr[t], v1 = xr[t + 256], v2 = xr[t + 512];
  float s  = v0 + v1 + v2;
  float s2 = v0 * v0 + v1 * v1 + v2 * v2;
#pragma unroll
  for (int off = 32; off > 0; off >>= 1) {
    s  += __shfl_down(s, off);
    s2 += __shfl_down(s2, off);
  }
  __shared__ float ws_[4], ws2_[4];
  if ((t & 63) == 0) { ws_[t >> 6] = s; ws2_[t >> 6] = s2; }
  __syncthreads();
  const float S  = ws_[0] + ws_[1] + ws_[2] + ws_[3];
  const float S2 = ws2_[0] + ws2_[1] + ws2_[2] + ws2_[3];
  const float mu  = S * (1.0f / Cc);
  const float inv = rsqrtf(S2 * (1.0f / Cc) - mu * mu + EPS_);
  bf16_t* orow = out + (size_t)row * Cc;
  orow[t]       = (bf16_t)((v0 - mu) * inv * w[t]       + b[t]);
  orow[t + 256] = (bf16_t)((v1 - mu) * inv * w[t + 256] + b[t + 256]);
  orow[t + 512] = (bf16_t)((v2 - mu) * inv * w[t + 512] + b[t + 512]);
}

// ---------------------------------------------------------------------------
// bf16 MFMA GEMM: 128x128 tile, BK=64, unpadded LDS (32 KB), XOR-swizzled
// chunk slots (slot s of row r holds global chunk s^(r&7)), global_load_lds
// staging.  EPI: 0 = fused qkv scatter, 3 = gelu->bf16.
// ---------------------------------------------------------------------------
template <int EPI>
__global__ __launch_bounds__(256, 3) void gemm_kernel(
    const bf16_t* __restrict__ A, const bf16_t* __restrict__ W,
    int K, int F,
    const float* __restrict__ bias, void* __restrict__ outp) {
  __shared__ alignas(16) bf16_t ldsA[128 * 64];
  __shared__ alignas(16) bf16_t ldsB[128 * 64];
  const int t = threadIdx.x, wave = t >> 6, lane = t & 63;
  const int quad = lane >> 4, l16 = lane & 15;
  const int wm = (wave & 1) * 64, wn = (wave >> 1) * 64;
  const int f0 = blockIdx.x * 128, r0 = blockIdx.y * 128;
  // staging: 8 rows x 8 chunk-slots per instr; slot s fetches global chunk
  // s^(row&7) so LDS slot s of row r holds chunk s^(r&7).
  const int srow = lane >> 3;
  const int scol = (((lane & 7) ^ (srow & 7)) * 8);

  const bf16_t* ga = A + (size_t)(r0 + wave * 32 + srow) * K + scol;
  const bf16_t* gb = W + (size_t)(f0 + wave * 32 + srow) * K + scol;
  bf16_t* la = &ldsA[(wave * 32) * 64];
  bf16_t* lb = &ldsB[(wave * 32) * 64];

  floatx4 acc[4][4] = {};

  for (int k0 = 0; k0 < K; k0 += 64) {
    __syncthreads();
#pragma unroll
    for (int j = 0; j < 4; j++) {
      async16(la + j * 512, ga + k0 + (size_t)(8 * j) * K);
      async16(lb + j * 512, gb + k0 + (size_t)(8 * j) * K);
    }
    __syncthreads();

#pragma unroll
    for (int ks = 0; ks < 2; ks++) {
      bf16x8 af[4], bfr[4];
#pragma unroll
      for (int mt = 0; mt < 4; mt++)
        af[mt] = *(const bf16x8*)&ldsA[(wm + mt * 16 + l16) * 64 +
                                       (((ks * 4 + quad) ^ (l16 & 7)) * 8)];
#pragma unroll
      for (int nt = 0; nt < 4; nt++)
        bfr[nt] = *(const bf16x8*)&ldsB[(wn + nt * 16 + l16) * 64 +
                                        (((ks * 4 + quad) ^ (l16 & 7)) * 8)];
#pragma unroll
      for (int mt = 0; mt < 4; mt++)
#pragma unroll
        for (int nt = 0; nt < 4; nt++)
          acc[mt][nt] = mfma16(af[mt], bfr[nt], acc[mt][nt]);
    }
  }

#pragma unroll
  for (int mt = 0; mt < 4; mt++) {
#pragma unroll
    for (int nt = 0; nt < 4; nt++) {
#pragma unroll
      for (int rg = 0; rg < 4; rg++) {
        const int r = r0 + wm + mt * 16 + quad * 4 + rg;
        const int f = f0 + wn + nt * 16 + l16;
        const float v = acc[mt][nt][rg];
        if constexpr (EPI == 0) {
          const int b = r >> 10, n = r & 1023;
          bf16_t* qkv = (bf16_t*)outp;
          if (f < 1536) {
            const int h = f >> 7, d = f & 127;
            qkv[(((size_t)(b * Hh + h)) * Nn + n) * 128 + d] = (bf16_t)v;
          } else if (f < 3072) {
            const int f2 = f - 1536, h = f2 >> 7, d = f2 & 127;
            (qkv + (size_t)Rr * 1536)
                [(((size_t)(b * Hh + h)) * Nn + n) * 128 + d] = (bf16_t)v;
          } else {
            const int f2 = f - 3072, h = f2 >> 7, d = f2 & 127;
            (qkv + (size_t)2 * Rr * 1536)
                [(((size_t)(b * Hh + h)) * 128 + d) * Nn + n] = (bf16_t)v;
          }
        } else {
          const float z = v + bias[f];
          const float g = 0.5f * z * (1.0f + erff(z * 0.70710678118f));
          ((bf16_t*)outp)[(size_t)r * F + f] = (bf16_t)g;
        }
      }
    }
  }
}

// ---------------------------------------------------------------------------
// 64x128-tile GEMM for F=768 outputs (proj, fc2): grid (6, 64) = 384 blocks.
// BK=64, XOR-swizzled like gemm_kernel.  f32 out = acc + bias[f] + resid.
// ---------------------------------------------------------------------------
__global__ __launch_bounds__(256, 4) void gemm64_kernel(
    const bf16_t* __restrict__ A, const bf16_t* __restrict__ W,
    int K, int F,
    const float* __restrict__ bias, const float* __restrict__ resid,
    float* __restrict__ outp) {
  __shared__ alignas(16) bf16_t ldsA[64 * 64];
  __shared__ alignas(16) bf16_t ldsB[128 * 64];
  const int t = threadIdx.x, wave = t >> 6, lane = t & 63;
  const int quad = lane >> 4, l16 = lane & 15;
  const int wm = (wave & 1) * 32, wn = (wave >> 1) * 64;
  const int f0 = blockIdx.x * 128, r0 = blockIdx.y * 64;
  const int srow = lane >> 3;
  const int scol = (((lane & 7) ^ (srow & 7)) * 8);

  const bf16_t* ga = A + (size_t)(r0 + wave * 16 + srow) * K + scol;
  const bf16_t* gb = W + (size_t)(f0 + wave * 32 + srow) * K + scol;
  bf16_t* la = &ldsA[(wave * 16) * 64];
  bf16_t* lb = &ldsB[(wave * 32) * 64];

  floatx4 acc[2][4] = {};

  for (int k0 = 0; k0 < K; k0 += 64) {
    __syncthreads();
#pragma unroll
    for (int j = 0; j < 2; j++)
      async16(la + j * 512, ga + k0 + (size_t)(8 * j) * K);
#pragma unroll
    for (int j = 0; j < 4; j++)
      async16(lb + j * 512, gb + k0 + (size_t)(8 * j) * K);
    __syncthreads();

#pragma unroll
    for (int ks = 0; ks < 2; ks++) {
      bf16x8 af[2], bfr[4];
#pragma unroll
      for (int mt = 0; mt < 2; mt++)
        af[mt] = *(const bf16x8*)&ldsA[(wm + mt * 16 + l16) * 64 +
                                       (((ks * 4 + quad) ^ (l16 & 7)) * 8)];
#pragma unroll
      for (int nt = 0; nt < 4; nt++)
        bfr[nt] = *(const bf16x8*)&ldsB[(wn + nt * 16 + l16) * 64 +
                                        (((ks * 4 + quad) ^ (l16 & 7)) * 8)];
#pragma unroll
      for (int mt = 0; mt < 2; mt++)
#pragma unroll
        for (int nt = 0; nt < 4; nt++)
          acc[mt][nt] = mfma16(af[mt], bfr[nt], acc[mt][nt]);
    }
  }

#pragma unroll
  for (int mt = 0; mt < 2; mt++)
#pragma unroll
    for (int nt = 0; nt < 4; nt++)
#pragma unroll
      for (int rg = 0; rg < 4; rg++) {
        const int r = r0 + wm + mt * 16 + quad * 4 + rg;
        const int f = f0 + wn + nt * 16 + l16;
        outp[(size_t)r * F + f] =
            acc[mt][nt][rg] + bias[f] + resid[(size_t)r * F + f];
      }
}

// ---------------------------------------------------------------------------
// Differential attention (unchanged from R5: head-major grid, 71.5 us).
// Block = 128 q-rows x 1 head; 4 waves x 32 q.  grid (48 bh, 8 qblk):
// head h -> XCD h%8 for every q-block (48 % 8 == 0), so K/V stay L2-resident.
// S^T formulation: A=K-frag, B=Q-frag => C holds S^T[key=quad*4+rg][q=l16];
// exp2 (Q pre-scaled), pack 4 keys -> ds_write_b64 into P[q][key] (stride 72),
// read back as PV A-frags (b128).  K/V staged with global_load_lds using a
// row-XOR chunk permutation on the GLOBAL side (LDS dest is lane-linear):
//   K [64][128]: 16B slot s of row r holds chunk ((s>>2)^(r&3), s&3)
//   V [128][64]: 16B slot s of row r holds key-slot  s^(r&7)
// No running max: |s*log2e/8| small, exp2 safe in f32; softmax is
// shift-invariant so result is exact.  Epilogue: lambda combine, head-LN,
// *0.8, store to (B,N,1536).
// ---------------------------------------------------------------------------
__global__ __launch_bounds__(256, 2) void attn_kernel(
    const bf16_t* __restrict__ Q, const bf16_t* __restrict__ Kk,
    const bf16_t* __restrict__ Vt, const float* __restrict__ lam,
    const float* __restrict__ lnw, const float* __restrict__ lnb,
    bf16_t* __restrict__ outp) {
  const int bh = blockIdx.x, qblk = blockIdx.y;  // head-major: XCD = bh % 8
  const bf16_t* qp = Q  + (size_t)bh * Nn * 128;   // [n][d]
  const bf16_t* kp = Kk + (size_t)bh * Nn * 128;   // [n][d]
  const bf16_t* vp = Vt + (size_t)bh * 128 * Nn;   // [d][n]

  __shared__ alignas(16) bf16_t ldsK[64 * 128];        // [key][d], swizzled
  __shared__ alignas(16) bf16_t ldsV[128 * 64];        // [d][key], swizzled
  __shared__ alignas(16) bf16_t ldsP[4][2][2][16 * 72];// [wave][mat][qg][q][key]

  const int t = threadIdx.x, wave = t >> 6, lane = t & 63;
  const int quad = lane >> 4, l16 = lane & 15;

  // Q B-frags: lane holds Q[q = qg*16+l16][d = c*32+quad*8+j]
  bf16x8 bq[2][4];
#pragma unroll
  for (int qg = 0; qg < 2; qg++) {
    const size_t qrow = qblk * 128 + wave * 32 + qg * 16 + l16;
#pragma unroll
    for (int c = 0; c < 4; c++)
      bq[qg][c] = *(const bf16x8*)(qp + qrow * 128 + c * 32 + quad * 8);
  }

  // staging addresses (per-lane constants)
  const int ksg = wave * 4;                      // K segs ksg..ksg+3
  const int krl = lane >> 4, kslot = lane & 15;  // 4 rows x 16 slots
  const int vrl = lane >> 3, vslot = lane & 7;   // 8 rows x 8 slots

  floatx4 o1[2][8] = {}, o2[2][8] = {};
  float l1a[2] = {0.f, 0.f}, l2a[2] = {0.f, 0.f};

  for (int kt = 0; kt < 16; kt++) {
    __syncthreads();
#pragma unroll
    for (int j = 0; j < 4; j++) {
      const int seg = ksg + j;
      {  // K: rows seg*4..+3
        const int r = seg * 4 + krl;
        const int cg = (kslot >> 2) ^ (r & 3), ci = kslot & 3;
        async16(&ldsK[seg * 512],
                kp + (size_t)(kt * 64 + r) * 128 + cg * 32 + ci * 8);
      }
      {  // V: rows seg*8..+7
        const int r = seg * 8 + vrl;
        const int sg = vslot ^ (r & 7);
        async16(&ldsV[seg * 512], vp + (size_t)r * Nn + kt * 64 + sg * 8);
      }
    }
    __syncthreads();

    // ---- S^T + exp2 + pack + P write ----
#pragma unroll
    for (int ktile = 0; ktile < 4; ktile++) {
      bf16x8 ak[4];
#pragma unroll
      for (int c = 0; c < 4; c++)
        ak[c] = *(const bf16x8*)&ldsK[(ktile * 16 + l16) * 128 +
                                      ((c ^ (l16 & 3)) * 32) + quad * 8];
#pragma unroll
      for (int qg = 0; qg < 2; qg++) {
        floatx4 s1 = {}, s2 = {};
        s1 = mfma16(ak[0], bq[qg][0], s1);
        s1 = mfma16(ak[1], bq[qg][1], s1);
        s2 = mfma16(ak[2], bq[qg][2], s2);
        s2 = mfma16(ak[3], bq[qg][3], s2);
        bf16x4 p1, p2;
        float a1 = 0.f, a2 = 0.f;
#pragma unroll
        for (int rg = 0; rg < 4; rg++) {
          const float e1 = __builtin_amdgcn_exp2f(s1[rg]);
          const float e2 = __builtin_amdgcn_exp2f(s2[rg]);
          p1[rg] = (__bf16)e1; p2[rg] = (__bf16)e2;
          a1 += (float)p1[rg]; a2 += (float)p2[rg];
        }
        l1a[qg] += a1; l2a[qg] += a2;
        const int po = l16 * 72 + ktile * 16 + quad * 4;
        *(bf16x4*)&ldsP[wave][0][qg][po] = p1;
        *(bf16x4*)&ldsP[wave][1][qg][po] = p2;
      }
    }

    // ---- PV ----  (P is wave-private; DS pipe orders the RAW per wave)
    bf16x8 ap1[2][2], ap2[2][2];
#pragma unroll
    for (int qg = 0; qg < 2; qg++)
#pragma unroll
      for (int c = 0; c < 2; c++) {
        const int po = l16 * 72 + c * 32 + quad * 8;
        ap1[qg][c] = *(const bf16x8*)&ldsP[wave][0][qg][po];
        ap2[qg][c] = *(const bf16x8*)&ldsP[wave][1][qg][po];
      }
#pragma unroll
    for (int dt = 0; dt < 8; dt++) {
      const int r = dt * 16 + l16;
      bf16x8 bv[2];
#pragma unroll
      for (int c = 0; c < 2; c++)
        bv[c] = *(const bf16x8*)&ldsV[r * 64 + (((c * 4 + quad) ^ (r & 7)) * 8)];
#pragma unroll
      for (int qg = 0; qg < 2; qg++) {
        o1[qg][dt] = mfma16(ap1[qg][0], bv[0], o1[qg][dt]);
        o1[qg][dt] = mfma16(ap1[qg][1], bv[1], o1[qg][dt]);
        o2[qg][dt] = mfma16(ap2[qg][0], bv[0], o2[qg][dt]);
        o2[qg][dt] = mfma16(ap2[qg][1], bv[1], o2[qg][dt]);
      }
    }
  }

  // l sums: lane holds partials for query (qg, l16) over its quad's keys.
#pragma unroll
  for (int qg = 0; qg < 2; qg++) {
    l1a[qg] += __shfl_xor(l1a[qg], 16); l1a[qg] += __shfl_xor(l1a[qg], 32);
    l2a[qg] += __shfl_xor(l2a[qg], 16); l2a[qg] += __shfl_xor(l2a[qg], 32);
  }

  const float lambda = *lam;
  const int b = bh / Hh, h = bh % Hh;

#pragma unroll
  for (int qg = 0; qg < 2; qg++) {
    // redistribute l: lane needs query row quad*4+rg (value lives in lane qr)
    float inv1[4], inv2[4];
#pragma unroll
    for (int rg = 0; rg < 4; rg++) {
      const int qr = quad * 4 + rg;
      inv1[rg] = 1.0f / __shfl(l1a[qg], qr);
      inv2[rg] = lambda / __shfl(l2a[qg], qr);
    }
    float vals[8][4];
    float sum[4] = {0.f, 0.f, 0.f, 0.f}, ssq[4] = {0.f, 0.f, 0.f, 0.f};
#pragma unroll
    for (int dt = 0; dt < 8; dt++)
#pragma unroll
      for (int rg = 0; rg < 4; rg++) {
        const float v = o1[qg][dt][rg] * inv1[rg] - o2[qg][dt][rg] * inv2[rg];
        vals[dt][rg] = v;
        sum[rg] += v; ssq[rg] += v * v;
      }
#pragma unroll
    for (int m = 8; m >= 1; m >>= 1)
#pragma unroll
      for (int rg = 0; rg < 4; rg++) {
        sum[rg] += __shfl_xor(sum[rg], m);
        ssq[rg] += __shfl_xor(ssq[rg], m);
      }
#pragma unroll
    for (int rg = 0; rg < 4; rg++) {
      const float mu  = sum[rg] * (1.0f / 128.0f);
      const float inv = rsqrtf(ssq[rg] * (1.0f / 128.0f) - mu * mu + EPS_);
      const int n = qblk * 128 + wave * 32 + qg * 16 + quad * 4 + rg;
      bf16_t* orow = outp + ((size_t)(b * Nn + n)) * 1536 + h * 128;
#pragma unroll
      for (int dt = 0; dt < 8; dt++) {
        const int d = dt * 16 + l16;
        orow[d] = (bf16_t)(((vals[dt][rg] - mu) * inv * lnw[d] + lnb[d]) * 0.8f);
      }
    }
  }
}

// ---------------------------------------------------------------------------
extern "C" void kernel_launch(void* const* d_in, const int* in_sizes, int n_in,
                              void* d_out, int out_size, void* d_ws,
                              size_t ws_size, hipStream_t stream) {
  (void)in_sizes; (void)n_in; (void)out_size; (void)ws_size;
  const float* x     = (const float*)d_in[0];
  const float* n1w   = (const float*)d_in[1];
  const float* n1b   = (const float*)d_in[2];
  const float* wq    = (const float*)d_in[3];
  const float* wk    = (const float*)d_in[4];
  const float* wv    = (const float*)d_in[5];
  const float* lam   = (const float*)d_in[6];
  const float* alnw  = (const float*)d_in[7];
  const float* alnb  = (const float*)d_in[8];
  const float* projw = (const float*)d_in[9];
  const float* projb = (const float*)d_in[10];
  const float* n2w   = (const float*)d_in[11];
  const float* n2b   = (const float*)d_in[12];
  const float* fc1w  = (const float*)d_in[13];
  const float* fc1b  = (const float*)d_in[14];
  const float* fc2w  = (const float*)d_in[15];
  const float* fc2b  = (const float*)d_in[16];
  float* out = (float*)d_out;

  char* p = (char*)d_ws;
  bf16_t* xn    = (bf16_t*)p; p += (size_t)Rr * Cc * 2;       // 6.3 MB
  bf16_t* wbuf  = (bf16_t*)p; p += (size_t)9437184 * 2;       // 18.9 MB
  bf16_t* qkv   = (bf16_t*)p; p += (size_t)3 * Rr * 1536 * 2; // 37.7 MB
  bf16_t* attnb = (bf16_t*)p; p += (size_t)Rr * 1536 * 2;     // 12.6 MB
  float*  xmid  = (float*)p;  p += (size_t)Rr * Cc * 4;       // 12.6 MB
  bf16_t* xn2   = (bf16_t*)p; p += (size_t)Rr * Cc * 2;       // 6.3 MB
  bf16_t* hb    = (bf16_t*)p; p += (size_t)Rr * 3072 * 2;     // 25.2 MB

  bf16_t* wqkv_b = wbuf;                 // rows 0..4607 (wq|wk|wv), K=768
  bf16_t* wpj_b  = wbuf + 3538944;
  bf16_t* wf1_b  = wbuf + 4718592;
  bf16_t* wf2_b  = wbuf + 7077888;

  convert_weights<<<9216, 256, 0, stream>>>(wq, wk, wv, projw, fc1w, fc2w, wbuf);
  ln_kernel<<<Rr, 256, 0, stream>>>(x, n1w, n1b, xn);

  gemm_kernel<0><<<dim3(36, 32), 256, 0, stream>>>(xn, wqkv_b, 768, 4608,
                                                   nullptr, qkv);

  const bf16_t* qb  = qkv;
  const bf16_t* kb  = qkv + (size_t)Rr * 1536;
  const bf16_t* vtb = qkv + (size_t)2 * Rr * 1536;
  attn_kernel<<<dim3(48, 8), 256, 0, stream>>>(qb, kb, vtb, lam, alnw, alnb,
                                               attnb);

  gemm64_kernel<<<dim3(6, 64), 256, 0, stream>>>(attnb, wpj_b, 1536, 768,
                                                 projb, x, xmid);
  ln_kernel<<<Rr, 256, 0, stream>>>(xmid, n2w, n2b, xn2);
  gemm_kernel<3><<<dim3(24, 32), 256, 0, stream>>>(xn2, wf1_b, 768, 3072,
                                                   fc1b, hb);
  gemm64_kernel<<<dim3(6, 64), 256, 0, stream>>>(hb, wf2_b, 3072, 768,
                                                 fc2b, xmid, out);
}